// Round 1
// baseline (66.967 us; speedup 1.0000x reference)
//
#include <hip/hip_runtime.h>

// out[b,y,:] = sum_{a=0}^{floor(y/8)} (k[b,y,:]·q[b,8a,:]) * v[b,8a,:]
// T=2048, K=8 (256 anchors), E=64, B=8, fp32 in/out.

constexpr int T_LEN = 2048;
constexpr int KSTR  = 8;
constexpr int EDIM  = 64;
constexpr int ROWS  = 16;            // rows per block
constexpr int NT    = T_LEN / ROWS;  // 128 tiles per batch

__global__ __launch_bounds__(256, 4)
void sparse_head2_fp32(const float* __restrict__ kk,
                       const float* __restrict__ qq,
                       const float* __restrict__ vv,
                       float* __restrict__ out, int B)
{
    // Work-balanced (b, tile) mapping: the 4 grid-quarters hand out
    // complementary tiles (base, NT-1-base, NT/4+base, NT-1-NT/4-base)
    // so each CU's set of blocks has ~constant total anchor work.
    int bid   = blockIdx.x;
    int per_q = B * (NT / 4);
    int q2    = bid / per_q;          // 0..3
    int jj    = bid % per_q;
    int b     = jj % B;
    int base  = jj / B;               // 0..NT/4-1
    int tile;
    switch (q2) {
        case 0:  tile = base;                 break;
        case 1:  tile = NT - 1 - base;        break;
        case 2:  tile = NT / 4 + base;        break;
        default: tile = NT - 1 - NT/4 - base; break;
    }
    int y0 = tile * ROWS;

    int t   = threadIdx.x;
    int r   = t >> 4;      // row within tile, 0..15
    int sub = t & 15;      // 16 threads per row
    int e0  = sub * 4;     // 4 contiguous e-elements per thread
    int y   = y0 + r;

    const float* krow = kk + ((size_t)b * T_LEN + y) * EDIM + e0;
    const float* qp   = qq + (size_t)b * T_LEN * EDIM + e0;
    const float* vp   = vv + (size_t)b * T_LEN * EDIM + e0;

    float4 kr = *(const float4*)krow;
    float accx = 0.f, accy = 0.f, accz = 0.f, accw = 0.f;

    // rows within one wave span 4 consecutive y inside one 8-row octet
    // (y0 multiple of 16) -> loop bound is wave-uniform.
    int A = (y >> 3) + 1;
    constexpr int STEP = KSTR * EDIM;   // floats between anchor rows

    #pragma unroll 4
    for (int a = 0; a < A; ++a) {
        float4 qv = *(const float4*)(qp + (size_t)a * STEP);
        float p = kr.x * qv.x + kr.y * qv.y;
        p += kr.z * qv.z;
        p += kr.w * qv.w;
        // reduce across the 16-lane group (masks stay in-group)
        p += __shfl_xor(p, 1);
        p += __shfl_xor(p, 2);
        p += __shfl_xor(p, 4);
        p += __shfl_xor(p, 8);
        float4 vl = *(const float4*)(vp + (size_t)a * STEP);
        accx += p * vl.x;
        accy += p * vl.y;
        accz += p * vl.z;
        accw += p * vl.w;
    }

    float4 o = make_float4(accx, accy, accz, accw);
    *(float4*)(out + ((size_t)b * T_LEN + y) * EDIM + e0) = o;
}

extern "C" void kernel_launch(void* const* d_in, const int* in_sizes, int n_in,
                              void* d_out, int out_size, void* d_ws, size_t ws_size,
                              hipStream_t stream) {
    const float* kk = (const float*)d_in[0];
    const float* qq = (const float*)d_in[1];
    const float* vv = (const float*)d_in[2];
    float* o        = (float*)d_out;
    int B = in_sizes[0] / (T_LEN * EDIM);
    int grid = B * NT;
    sparse_head2_fp32<<<grid, 256, 0, stream>>>(kk, qq, vv, o, B);
}

// Round 2
// 12.412 us; speedup vs baseline: 5.3952x; 5.3952x over previous
//
#include <hip/hip_runtime.h>
#include <hip/hip_bf16.h>

// out[b,y,:] = sum_{a=0}^{y>>3} (k[b,y,:]·q[b,8a,:]) * v[b,8a,:]
// T=2048, anchors=256 (stride 8), E=64, fp32 in/out. MFMA bf16 formulation:
// per 32-row tile: S[32x32] = K·Qa^T (masked), out += S·Va, anchor-tiles of 32.

constexpr int T_LEN = 2048;
constexpr int EDIM  = 64;
constexpr int ROWS  = 32;             // rows per tile
constexpr int NTILE = T_LEN / ROWS;   // 64 tiles per batch
constexpr int TE    = T_LEN * EDIM;

typedef __attribute__((ext_vector_type(4))) float f32x4;
typedef __attribute__((ext_vector_type(8))) short bf16x8;

__device__ __forceinline__ short f2bf(float f) {
    __hip_bfloat16 h = __float2bfloat16(f);
    return __builtin_bit_cast(short, h);
}

__device__ __forceinline__ bf16x8 pack8(f32x4 a, f32x4 b) {
    bf16x8 r;
    r[0] = f2bf(a[0]); r[1] = f2bf(a[1]); r[2] = f2bf(a[2]); r[3] = f2bf(a[3]);
    r[4] = f2bf(b[0]); r[5] = f2bf(b[1]); r[6] = f2bf(b[2]); r[7] = f2bf(b[3]);
    return r;
}

__device__ __forceinline__ bf16x8 pack8a(const float* v) {
    bf16x8 r;
    #pragma unroll
    for (int i = 0; i < 8; ++i) r[i] = f2bf(v[i]);
    return r;
}

// One 32-row tile: this wave handles anchor-tiles with index ≡ wpar (mod 2).
__device__ __forceinline__ void run_tile(const float* __restrict__ kb,
                                         const float* __restrict__ qb,
                                         const float* __restrict__ vb,
                                         int y0, int wpar, int lane,
                                         short* sl, f32x4 (&acc)[2][4])
{
    const int g  = lane >> 4;    // 0..3
    const int ln = lane & 15;

    // K A-frags, resident for whole tile: Kf[mt][eh], k-index = eh*32 + 8g + i
    bf16x8 Kf[2][2];
    #pragma unroll
    for (int mt = 0; mt < 2; ++mt)
        #pragma unroll
        for (int eh = 0; eh < 2; ++eh) {
            const float* p = kb + (size_t)(y0 + mt * 16 + ln) * EDIM + eh * 32 + g * 8;
            Kf[mt][eh] = pack8(*(const f32x4*)p, *(const f32x4*)(p + 4));
        }

    const int amax = (y0 + ROWS - 1) >> 3;   // last valid anchor for this tile
    const int nat  = (amax >> 5) + 1;        // number of 32-anchor tiles

    for (int ai = wpar; ai < nat; ai += 2) {
        const int a0 = ai * 32;

        // ---- issue Q loads (stage-1 B-frag layout), fp32 ----
        f32x4 qraw[2][2][2];   // [nt][eh][half]
        #pragma unroll
        for (int nt = 0; nt < 2; ++nt)
            #pragma unroll
            for (int eh = 0; eh < 2; ++eh) {
                const float* p = qb + (size_t)(8 * (a0 + nt * 16 + ln)) * EDIM + eh * 32 + g * 8;
                qraw[nt][eh][0] = *(const f32x4*)p;
                qraw[nt][eh][1] = *(const f32x4*)(p + 4);
            }

        // ---- issue V loads (stage-2 B-frag layout: n=e col, k=anchor) ----
        float vraw[4][8];      // [et][i]; anchor = a0 + 8g + i, e = et*16 + ln
        {
            const float* pv = vb + (size_t)(8 * (a0 + 8 * g)) * EDIM + ln;
            #pragma unroll
            for (int i = 0; i < 8; ++i)
                #pragma unroll
                for (int et = 0; et < 4; ++et)
                    vraw[et][i] = pv[(size_t)i * 8 * EDIM + et * 16];
        }

        // ---- stage 1: S = K · Qa^T  (2x2 tiles of 16x16, K=64 via 2 MFMAs) ----
        bf16x8 Qf[2][2];
        #pragma unroll
        for (int nt = 0; nt < 2; ++nt)
            #pragma unroll
            for (int eh = 0; eh < 2; ++eh)
                Qf[nt][eh] = pack8(qraw[nt][eh][0], qraw[nt][eh][1]);

        f32x4 S[2][2];
        #pragma unroll
        for (int mt = 0; mt < 2; ++mt)
            #pragma unroll
            for (int nt = 0; nt < 2; ++nt) {
                f32x4 s = {0.f, 0.f, 0.f, 0.f};
                s = __builtin_amdgcn_mfma_f32_16x16x32_bf16(Kf[mt][0], Qf[nt][0], s, 0, 0, 0);
                s = __builtin_amdgcn_mfma_f32_16x16x32_bf16(Kf[mt][1], Qf[nt][1], s, 0, 0, 0);
                S[mt][nt] = s;
            }

        // ---- mask partial anchors (only ever triggers in last a-tile) ----
        if (ai == nat - 1) {
            #pragma unroll
            for (int mt = 0; mt < 2; ++mt)
                #pragma unroll
                for (int nt = 0; nt < 2; ++nt)
                    #pragma unroll
                    for (int r = 0; r < 4; ++r) {
                        int y = y0 + mt * 16 + g * 4 + r;
                        int a = a0 + nt * 16 + ln;
                        if (8 * a > y) S[mt][nt][r] = 0.f;
                    }
        }

        // ---- S -> LDS (bf16, XOR-swizzled 16B chunks) ----
        #pragma unroll
        for (int mt = 0; mt < 2; ++mt)
            #pragma unroll
            for (int nt = 0; nt < 2; ++nt)
                #pragma unroll
                for (int r = 0; r < 4; ++r) {
                    int row = mt * 16 + g * 4 + r;
                    int a   = nt * 16 + ln;
                    sl[row * 32 + (((a >> 3) ^ (row & 3)) << 3) + (a & 7)] = f2bf(S[mt][nt][r]);
                }

        // ---- read S back as stage-2 A-frags: m=row (lane&15), k=anchor 8g+i ----
        bf16x8 SA[2];
        #pragma unroll
        for (int mt = 0; mt < 2; ++mt) {
            int row = mt * 16 + ln;
            SA[mt] = *(const bf16x8*)(sl + row * 32 + ((g ^ (row & 3)) << 3));
        }

        // ---- stage 2: out += S · Va  (2 mt x 4 et tiles, K=32 anchors) ----
        #pragma unroll
        for (int et = 0; et < 4; ++et) {
            bf16x8 Vf = pack8a(vraw[et]);
            #pragma unroll
            for (int mt = 0; mt < 2; ++mt)
                acc[mt][et] = __builtin_amdgcn_mfma_f32_16x16x32_bf16(SA[mt], Vf, acc[mt][et], 0, 0, 0);
        }
    }
}

__device__ __forceinline__ void write_partial(float (*pb)[EDIM], f32x4 (&acc)[2][4],
                                              int g, int ln)
{
    #pragma unroll
    for (int mt = 0; mt < 2; ++mt)
        #pragma unroll
        for (int et = 0; et < 4; ++et)
            #pragma unroll
            for (int r = 0; r < 4; ++r) {
                int row = mt * 16 + g * 4 + r;
                int e   = et * 16 + ln;
                pb[row][e ^ ((row & 3) << 2)] = acc[mt][et][r];
            }
}

__device__ __forceinline__ void store_add(float* o, float (*pb)[EDIM],
                                          f32x4 (&acc)[2][4], int g, int ln)
{
    #pragma unroll
    for (int mt = 0; mt < 2; ++mt)
        #pragma unroll
        for (int et = 0; et < 4; ++et)
            #pragma unroll
            for (int r = 0; r < 4; ++r) {
                int row = mt * 16 + g * 4 + r;
                int e   = et * 16 + ln;
                o[(size_t)row * EDIM + e] = acc[mt][et][r] + pb[row][e ^ ((row & 3) << 2)];
            }
}

__global__ __launch_bounds__(128, 1)
void sh2_mfma(const float* __restrict__ kk, const float* __restrict__ qq,
              const float* __restrict__ vv, float* __restrict__ out, int B)
{
    __shared__ alignas(16) short slds[2][ROWS * 32];  // per-wave S scratch (4 KB)
    __shared__ float pbuf[2][ROWS][EDIM];             // cross-wave partial sums (16 KB)

    const int bid  = blockIdx.x;
    const int p    = bid & 31;           // pair index 0..31
    const int b    = bid >> 5;           // batch
    const int w    = threadIdx.x >> 6;   // wave 0/1 = anchor parity
    const int lane = threadIdx.x & 63;
    const int g = lane >> 4, ln = lane & 15;

    const float* kb = kk + (size_t)b * TE;
    const float* qb = qq + (size_t)b * TE;
    const float* vb = vv + (size_t)b * TE;

    // complementary tile pair: work(p) + work(63-p) = 9 anchor-tiles, constant
    const int y0A = ROWS * p;
    const int y0B = ROWS * (NTILE - 1 - p);

    const f32x4 vzero = {0.f, 0.f, 0.f, 0.f};
    f32x4 accA[2][4], accB[2][4];
    #pragma unroll
    for (int i = 0; i < 2; ++i)
        #pragma unroll
        for (int j = 0; j < 4; ++j) { accA[i][j] = vzero; accB[i][j] = vzero; }

    run_tile(kb, qb, vb, y0A, w, lane, slds[w], accA);
    if (w == 1) write_partial(pbuf[0], accA, g, ln);

    run_tile(kb, qb, vb, y0B, w, lane, slds[w], accB);
    if (w == 0) write_partial(pbuf[1], accB, g, ln);

    __syncthreads();

    if (w == 0) store_add(out + (size_t)b * TE + (size_t)y0A * EDIM, pbuf[0], accA, g, ln);
    else        store_add(out + (size_t)b * TE + (size_t)y0B * EDIM, pbuf[1], accB, g, ln);
}

extern "C" void kernel_launch(void* const* d_in, const int* in_sizes, int n_in,
                              void* d_out, int out_size, void* d_ws, size_t ws_size,
                              hipStream_t stream) {
    const float* kk = (const float*)d_in[0];
    const float* qq = (const float*)d_in[1];
    const float* vv = (const float*)d_in[2];
    float* o        = (float*)d_out;
    int B = in_sizes[0] / TE;
    sh2_mfma<<<B * (NTILE / 2), 128, 0, stream>>>(kk, qq, vv, o, B);
}